// Round 6
// baseline (390.696 us; speedup 1.0000x reference)
//
#include <hip/hip_runtime.h>
#include <hip/hip_bf16.h>
#include <math.h>

// Problem constants (reference: B=8, S=1024, D=1024, E=8, F=2048, capacity 2 -> k=256)
#define B_   8
#define S_   1024
#define D_   1024
#define E_   8
#define F_   2048
#define KCAP 256

typedef __bf16 bf16x8 __attribute__((ext_vector_type(8)));
typedef float  floatx4 __attribute__((ext_vector_type(4)));

// ---- fp32 -> bf16 round-to-nearest-even (no NaN in this data) ----
__device__ __forceinline__ unsigned short f2b(float f) {
    union { float f; unsigned int u; } v; v.f = f;
    unsigned int u = v.u;
    u += 0x7fffu + ((u >> 16) & 1u);
    return (unsigned short)(u >> 16);
}

__device__ __forceinline__ void gl_lds16(const void* g, void* l) {
    __builtin_amdgcn_global_load_lds(
        (const __attribute__((address_space(1))) void*)g,
        (__attribute__((address_space(3))) void*)l, 16, 0, 0);
}

// sortable key: probs > 0 so float bits are monotonic; secondary index asc
// (larger (1023-s) wins ties -> smaller s, matching lax.top_k).
__device__ __forceinline__ unsigned long long topk_key(float p, int s) {
    return (((unsigned long long)__float_as_uint(p)) << 10) | (unsigned)(S_ - 1 - s);
}

// ---------------- 1. prep: router+softmax+x-cast  |  transpose w1  |  transpose w2  |  zero out --------
// Fused independent work, one launch. Blocks [0,2048): router (4 tokens each) + zero 16KB of out.
// Blocks [2048,6144): w1 [E][D][F] -> w1t [E][F][D] (64x64 tiles). Blocks [6144,10240): w2 likewise.
__device__ __forceinline__ void transpose64(const float* __restrict__ in, unsigned short* __restrict__ out,
                                            int R, int C, int rt, int ct, int tid, float (*tile)[65]) {
    int r0 = rt * 64, c0 = ct * 64;
    int row = tid >> 2, q = tid & 3;
    const float* src = in + (size_t)(r0 + row) * C + c0 + q * 16;
    float4 v0 = ((const float4*)src)[0];
    float4 v1 = ((const float4*)src)[1];
    float4 v2 = ((const float4*)src)[2];
    float4 v3 = ((const float4*)src)[3];
    float* tr = &tile[row][q * 16];
    tr[0]  = v0.x; tr[1]  = v0.y; tr[2]  = v0.z; tr[3]  = v0.w;
    tr[4]  = v1.x; tr[5]  = v1.y; tr[6]  = v1.z; tr[7]  = v1.w;
    tr[8]  = v2.x; tr[9]  = v2.y; tr[10] = v2.z; tr[11] = v2.w;
    tr[12] = v3.x; tr[13] = v3.y; tr[14] = v3.z; tr[15] = v3.w;
    __syncthreads();
    int c = tid >> 2;                                  // 0..63 across block
    unsigned short* dst = out + (size_t)(c0 + c) * R + r0 + q * 16;
#pragma unroll
    for (int k4 = 0; k4 < 4; k4++) {
        ushort4 o;
        o.x = f2b(tile[q * 16 + k4 * 4 + 0][c]);
        o.y = f2b(tile[q * 16 + k4 * 4 + 1][c]);
        o.z = f2b(tile[q * 16 + k4 * 4 + 2][c]);
        o.w = f2b(tile[q * 16 + k4 * 4 + 3][c]);
        ((ushort4*)dst)[k4] = o;
    }
}

__global__ __launch_bounds__(256) void prep_kernel(
    const float* __restrict__ x, const float* __restrict__ cw,
    const float* __restrict__ w1, const float* __restrict__ w2,
    float* __restrict__ probs, unsigned short* __restrict__ xb,
    unsigned short* __restrict__ w1t, unsigned short* __restrict__ w2t,
    float* __restrict__ out) {
    __shared__ float tile[64][65];                     // used by transpose roles only
    const int blk = blockIdx.x;
    const int tid = threadIdx.x;
    if (blk < 2048) {
        // zero out: 2048 blocks x 16KB = 33.5 MB (needed for gemm2's atomic scatter)
        float4 z = make_float4(0.f, 0.f, 0.f, 0.f);
        float4* oz = (float4*)out + blk * 1024 + tid;
        oz[0] = z; oz[256] = z; oz[512] = z; oz[768] = z;
        // router: one wave per token, fp32 logits+softmax, fused bf16 cast of x
        int gid  = blk * 256 + tid;
        int wave = gid >> 6;
        int lane = gid & 63;
        int b = wave >> 10;
        int s = wave & (S_ - 1);
        const float* xrow = x + ((size_t)b * S_ + s) * D_;
        unsigned short* xbrow = xb + ((size_t)b * S_ + s) * D_;
        float acc[E_];
#pragma unroll
        for (int e = 0; e < E_; e++) acc[e] = 0.f;
#pragma unroll
        for (int it = 0; it < D_ / 256; it++) {
            int i = it * 256 + lane * 4;
            float4 xv = *(const float4*)(xrow + i);
            ushort4 o;
            o.x = f2b(xv.x); o.y = f2b(xv.y); o.z = f2b(xv.z); o.w = f2b(xv.w);
            *(ushort4*)(xbrow + i) = o;
#pragma unroll
            for (int e = 0; e < E_; e++) {
                float4 wv = *(const float4*)(cw + e * D_ + i);   // 32KB table, L1-resident
                acc[e] = fmaf(xv.x, wv.x, fmaf(xv.y, wv.y, fmaf(xv.z, wv.z, fmaf(xv.w, wv.w, acc[e]))));
            }
        }
#pragma unroll
        for (int e = 0; e < E_; e++) {
            float v = acc[e];
#pragma unroll
            for (int off = 32; off >= 1; off >>= 1) v += __shfl_down(v, off, 64);
            acc[e] = v;
        }
        if (lane == 0) {
            float m = acc[0];
#pragma unroll
            for (int e = 1; e < E_; e++) m = fmaxf(m, acc[e]);
            float sum = 0.f;
#pragma unroll
            for (int e = 0; e < E_; e++) { acc[e] = __expf(acc[e] - m); sum += acc[e]; }
            float inv = 1.f / sum;
#pragma unroll
            for (int e = 0; e < E_; e++) probs[((size_t)b * E_ + e) * S_ + s] = acc[e] * inv;
        }
    } else if (blk < 6144) {
        int t = blk - 2048;                            // w1: R=D(16 rt), C=F(32 ct); 512 tiles/expert
        int e = t >> 9, rem = t & 511;
        transpose64(w1 + (size_t)e * D_ * F_, w1t + (size_t)e * F_ * D_,
                    D_, F_, rem >> 5, rem & 31, tid, tile);
    } else {
        int t = blk - 6144;                            // w2: R=F(32 rt), C=D(16 ct)
        int e = t >> 9, rem = t & 511;
        transpose64(w2 + (size_t)e * F_ * D_, w2t + (size_t)e * D_ * F_,
                    F_, D_, rem >> 4, rem & 15, tid, tile);
    }
}

// ---------------- 2a. partial rank counting: 256 blocks = 64 (b,e) x 4 t-chunks ----------------
__global__ void topk_rank_kernel(const float* __restrict__ probs, int* __restrict__ R4) {
    int g  = blockIdx.x;
    int be = g >> 2, c = g & 3;
    int tid = threadIdx.x;
    const float* rowp = probs + (size_t)be * S_;
    __shared__ unsigned long long kc[256];
    {
        int t = c * 256 + tid;
        kc[tid] = topk_key(rowp[t], t);
    }
    unsigned long long k[4];
    int r[4] = {0, 0, 0, 0};
#pragma unroll
    for (int q = 0; q < 4; q++) k[q] = topk_key(rowp[q * 256 + tid], q * 256 + tid);
    __syncthreads();
#pragma unroll 8
    for (int t = 0; t < 256; t++) {
        unsigned long long kt = kc[t];                 // LDS broadcast
#pragma unroll
        for (int q = 0; q < 4; q++) r[q] += (kt > k[q]);
    }
    int* Rb = R4 + (g << 10);                          // [be*4+c][1024]
#pragma unroll
    for (int q = 0; q < 4; q++) Rb[q * 256 + tid] = r[q];
}

// ---------------- 2b. finalize: sum partials, emit I/G ----------------
__global__ void topk_finalize_kernel(const float* __restrict__ probs, const int* __restrict__ R4,
                                     int* __restrict__ I, float* __restrict__ G) {
    int be = blockIdx.x;                               // one block per (b,e)
    int tid = threadIdx.x;
    const float* rowp = probs + (size_t)be * S_;
    const int* Rb = R4 + (be << 12);
#pragma unroll
    for (int q = 0; q < 4; q++) {
        int s = q * 256 + tid;
        int rank = Rb[s] + Rb[1024 + s] + Rb[2048 + s] + Rb[3072 + s];
        if (rank < KCAP) {
            I[be * KCAP + rank] = s;
            G[be * KCAP + rank] = rowp[s];
        }
    }
}

// ======== GEMM core notes ========
// BK=64, 128x128 tile, 4 sweeps of 256 x 16B staging; bank-conflict-free via 16B-segment
// permutation seg_stored(c) = c ^ (row & 7) (verified round 4: SQ_LDS_BANK_CONFLICT = 0).
// XCD swizzle: blockIdx % 8 = e, so all tiles sharing w*t[e] (4 MB = one XCD L2) co-locate
// (verified round 5: gemm1 FETCH_SIZE 173 -> 72 MB).

// ---------------- 3. GEMM1: H[be] = silu(gather(x, I[be]) @ w1[e]) ----------------
__global__ __launch_bounds__(256, 4) void gemm1_kernel(
    const unsigned short* __restrict__ xb,   // [B][S][D] bf16
    const unsigned short* __restrict__ w1t,  // [E][F][D] bf16
    const int* __restrict__ I,               // [B][E][KCAP]
    unsigned short* __restrict__ H)          // [B*E][KCAP][F] bf16
{
    const int g  = blockIdx.x;               // 2048 = 8 xcd * 8 b * 32 tiles
    const int e  = g & 7;                    // XCD id
    const int rr = g >> 3;
    const int b  = rr >> 5;
    const int t5 = rr & 31;
    const int be = b * 8 + e;
    const int mt = t5 & 1;          // 2 m-tiles (256/128)
    const int nt = t5 >> 1;         // 16 n-tiles (2048/128)
    const int tid = threadIdx.x;

    __shared__ __align__(16) unsigned short Asm[128 * 64];  // 16 KB
    __shared__ __align__(16) unsigned short Bsm[128 * 64];  // 16 KB
    __shared__ unsigned int ArowS[128];

    if (tid < 128) {
        int tok = I[(size_t)be * KCAP + mt * 128 + tid];
        ArowS[tid] = (unsigned)((b * S_ + tok) * D_);
    }
    __syncthreads();

    const int r8   = tid >> 3;                       // 0..31 (row within sweep)
    const int kseg = (tid & 7) ^ (r8 & 7);           // permuted 16B segment
    unsigned aoffW[4];
#pragma unroll
    for (int w = 0; w < 4; w++) aoffW[w] = ArowS[w * 32 + r8] + kseg * 8;
    const size_t boff0 = ((size_t)e * F_ + nt * 128 + r8) * D_ + kseg * 8;

    const int lane = tid & 63;
    const int wv   = tid >> 6;
    const int wm   = (wv & 1) * 64;
    const int wn   = (wv >> 1) * 64;
    const int l15  = lane & 15;
    const int quad = lane >> 4;
    const int x0   = (quad ^ (l15 & 7)) * 8;         // swizzled seg offset (elements)

    int aoffs[4], boffs[4];
#pragma unroll
    for (int i = 0; i < 4; i++) {
        aoffs[i] = (wm + i * 16 + l15) * 64 + x0;
        boffs[i] = (wn + i * 16 + l15) * 64 + x0;
    }

    floatx4 acc[4][4];
#pragma unroll
    for (int i = 0; i < 4; i++)
#pragma unroll
        for (int j = 0; j < 4; j++) acc[i][j] = (floatx4){0.f, 0.f, 0.f, 0.f};

    for (int k0 = 0; k0 < D_; k0 += 64) {
#pragma unroll
        for (int w = 0; w < 4; w++) {
            gl_lds16(xb  + aoffW[w] + k0,                    &Asm[(w * 256 + tid) * 8]);
            gl_lds16(w1t + boff0 + (size_t)w * 32 * D_ + k0, &Bsm[(w * 256 + tid) * 8]);
        }
        __syncthreads();
        bf16x8 af[4], bfr[4];
#pragma unroll
        for (int i = 0; i < 4; i++) {                 // k-half 0
            af[i]  = *(const bf16x8*)&Asm[aoffs[i]];
            bfr[i] = *(const bf16x8*)&Bsm[boffs[i]];
        }
#pragma unroll
        for (int i = 0; i < 4; i++)
#pragma unroll
            for (int j = 0; j < 4; j++)
                acc[i][j] = __builtin_amdgcn_mfma_f32_16x16x32_bf16(af[i], bfr[j], acc[i][j], 0, 0, 0);
#pragma unroll
        for (int i = 0; i < 4; i++) {                 // k-half 1: seg offset = x0 ^ 4 -> elem ^ 32
            af[i]  = *(const bf16x8*)&Asm[aoffs[i] ^ 32];
            bfr[i] = *(const bf16x8*)&Bsm[boffs[i] ^ 32];
        }
#pragma unroll
        for (int i = 0; i < 4; i++)
#pragma unroll
            for (int j = 0; j < 4; j++)
                acc[i][j] = __builtin_amdgcn_mfma_f32_16x16x32_bf16(af[i], bfr[j], acc[i][j], 0, 0, 0);
        __syncthreads();
    }

    // epilogue: silu -> H (bf16). C/D layout: row = quad*4+r, col = lane&15 (m89-verified)
    unsigned short* Hbe = H + (size_t)be * KCAP * F_;
#pragma unroll
    for (int i = 0; i < 4; i++) {
#pragma unroll
        for (int r = 0; r < 4; r++) {
            int m = mt * 128 + wm + i * 16 + quad * 4 + r;
            unsigned short* hrow = Hbe + (size_t)m * F_ + nt * 128;
#pragma unroll
            for (int j = 0; j < 4; j++) {
                float v = acc[i][j][r];
                float sv = v / (1.f + __expf(-v));
                hrow[wn + j * 16 + l15] = f2b(sv);
            }
        }
    }
}

// ---------------- 4. GEMM2: out[b, I[be,m], :] += G[be,m] * (H[be] @ w2[e])  (atomic scatter) ----------
__global__ __launch_bounds__(256, 4) void gemm2_kernel(
    const unsigned short* __restrict__ H,    // [B*E][KCAP][F] bf16
    const unsigned short* __restrict__ w2t,  // [E][D][F] bf16
    const int* __restrict__ I,
    const float* __restrict__ G,
    float* __restrict__ out)                 // [B][S][D] fp32, zeroed by prep
{
    const int g  = blockIdx.x;               // 1024 = 8 xcd * 8 b * 16 tiles
    const int e  = g & 7;                    // XCD id
    const int rr = g >> 3;
    const int b  = rr >> 4;
    const int t4 = rr & 15;
    const int be = b * 8 + e;
    const int mt = t4 & 1;          // 2 m-tiles
    const int nt = t4 >> 1;         // 8 n-tiles (1024/128)
    const int tid = threadIdx.x;

    __shared__ __align__(16) unsigned short Asm[128 * 64];
    __shared__ __align__(16) unsigned short Bsm[128 * 64];
    __shared__ unsigned int OrowS[128];
    __shared__ float Gs[128];

    if (tid < 128) {
        int tok = I[(size_t)be * KCAP + mt * 128 + tid];
        OrowS[tid] = (unsigned)((b * S_ + tok) * D_);
        Gs[tid] = G[(size_t)be * KCAP + mt * 128 + tid];
    }
    __syncthreads();

    const int r8   = tid >> 3;
    const int kseg = (tid & 7) ^ (r8 & 7);
    const size_t aoff0 = ((size_t)be * KCAP + mt * 128 + r8) * F_ + kseg * 8;
    const size_t boff0 = ((size_t)e * D_ + nt * 128 + r8) * F_ + kseg * 8;

    const int lane = tid & 63;
    const int wv   = tid >> 6;
    const int wm   = (wv & 1) * 64;
    const int wn   = (wv >> 1) * 64;
    const int l15  = lane & 15;
    const int quad = lane >> 4;
    const int x0   = (quad ^ (l15 & 7)) * 8;

    int aoffs[4], boffs[4];
#pragma unroll
    for (int i = 0; i < 4; i++) {
        aoffs[i] = (wm + i * 16 + l15) * 64 + x0;
        boffs[i] = (wn + i * 16 + l15) * 64 + x0;
    }

    floatx4 acc[4][4];
#pragma unroll
    for (int i = 0; i < 4; i++)
#pragma unroll
        for (int j = 0; j < 4; j++) acc[i][j] = (floatx4){0.f, 0.f, 0.f, 0.f};

    for (int k0 = 0; k0 < F_; k0 += 64) {
#pragma unroll
        for (int w = 0; w < 4; w++) {
            gl_lds16(H   + aoff0 + (size_t)w * 32 * F_ + k0, &Asm[(w * 256 + tid) * 8]);
            gl_lds16(w2t + boff0 + (size_t)w * 32 * F_ + k0, &Bsm[(w * 256 + tid) * 8]);
        }
        __syncthreads();
        bf16x8 af[4], bfr[4];
#pragma unroll
        for (int i = 0; i < 4; i++) {
            af[i]  = *(const bf16x8*)&Asm[aoffs[i]];
            bfr[i] = *(const bf16x8*)&Bsm[boffs[i]];
        }
#pragma unroll
        for (int i = 0; i < 4; i++)
#pragma unroll
            for (int j = 0; j < 4; j++)
                acc[i][j] = __builtin_amdgcn_mfma_f32_16x16x32_bf16(af[i], bfr[j], acc[i][j], 0, 0, 0);
#pragma unroll
        for (int i = 0; i < 4; i++) {
            af[i]  = *(const bf16x8*)&Asm[aoffs[i] ^ 32];
            bfr[i] = *(const bf16x8*)&Bsm[boffs[i] ^ 32];
        }
#pragma unroll
        for (int i = 0; i < 4; i++)
#pragma unroll
            for (int j = 0; j < 4; j++)
                acc[i][j] = __builtin_amdgcn_mfma_f32_16x16x32_bf16(af[i], bfr[j], acc[i][j], 0, 0, 0);
        __syncthreads();
    }

    // epilogue: weighted atomic scatter-add (token may be chosen by several experts)
#pragma unroll
    for (int i = 0; i < 4; i++) {
#pragma unroll
        for (int r = 0; r < 4; r++) {
            int m = wm + i * 16 + quad * 4 + r;           // local row in this 128-tile
            float gw = Gs[m];
            float* orow = out + OrowS[m] + nt * 128;
#pragma unroll
            for (int j = 0; j < 4; j++)
                atomicAdd(orow + wn + j * 16 + l15, gw * acc[i][j][r]);
        }
    }
}

// ---------------- launch ----------------
extern "C" void kernel_launch(void* const* d_in, const int* in_sizes, int n_in,
                              void* d_out, int out_size, void* d_ws, size_t ws_size,
                              hipStream_t stream) {
    const float* x  = (const float*)d_in[0];
    const float* cw = (const float*)d_in[1];
    const float* w1 = (const float*)d_in[2];
    const float* w2 = (const float*)d_in[3];
    float* out = (float*)d_out;

    // workspace layout (bytes), total 151,388,160 (== round-1 proven size).
    // R4 (1 MB partial-rank scratch) aliases Hbuf: consumed by finalize before gemm1 writes H.
    char* ws = (char*)d_ws;
    float*          probs = (float*)(ws);                        //   0.26 MB  [B][E][S]
    int*            Ibuf  = (int*)(ws + 262144);                 //  64 KB     [B][E][256]
    float*          Gbuf  = (float*)(ws + 327680);               //  64 KB
    unsigned short* xb    = (unsigned short*)(ws + 393216);      //  16.78 MB  x bf16
    unsigned short* w1t   = (unsigned short*)(ws + 17170432);    //  33.55 MB  [E][F][D]
    unsigned short* w2t   = (unsigned short*)(ws + 50724864);    //  33.55 MB  [E][D][F]
    unsigned short* Hbuf  = (unsigned short*)(ws + 84279296);    //  67.11 MB  [B*E][256][F]
    int*            R4    = (int*)Hbuf;                          //   1 MB     [64*4][1024] (aliased)

    prep_kernel<<<10240, 256, 0, stream>>>(x, cw, w1, w2, probs, xb, w1t, w2t, out);
    topk_rank_kernel<<<256, 256, 0, stream>>>(probs, R4);
    topk_finalize_kernel<<<B_ * E_, 256, 0, stream>>>(probs, R4, Ibuf, Gbuf);
    gemm1_kernel<<<B_ * E_ * 2 * (F_ / 128), 256, 0, stream>>>(xb, w1t, Ibuf, Hbuf);
    gemm2_kernel<<<B_ * E_ * 2 * (D_ / 128), 256, 0, stream>>>(Hbuf, w2t, Ibuf, Gbuf, out);
}